// Round 4
// baseline (54.720 us; speedup 1.0000x reference)
//
#include <hip/hip_runtime.h>
#include <math.h>

// Problem constants
#define B_   8
#define C1   256
#define HW1  4096   // 64*64
#define C2   512
#define HW2  1024   // 32*32

#define CCH  8      // channels per block
#define HWT  1024   // hw elements per block (256 threads * float4)
#define NCH1 32     // chunk count level 1 (C1/CCH)
#define NCH2 64     // chunk count level 2 (C2/CCH)
#define NT1  4      // hw tiles level 1 (HW1/HWT)
#define NT2  1      // hw tiles level 2

// grids
#define NB1  (B_*NT1*NCH1)   // 1024 level-1 stream blocks
#define NB2  (B_*NCH2)       // 512  level-2 stream blocks
#define NBS  (NB1+NB2)       // 1536

// ---------------- fast-path ws layout (floats); nothing read before written ----------------
#define F_LATP  0                          // 32 lat partials
#define F_SL1P  (F_LATP + 32)              // NB1 slam1 partials
#define F_SL2P  (F_SL1P + NB1)             // NB2 slam2 partials
#define F_AP1S  (F_SL2P + NB2)             // As1 partials [NCH1][B][HW1]
#define F_AP1T  (F_AP1S + NCH1*B_*HW1)
#define F_AP2S  (F_AP1T + NCH1*B_*HW1)     // As2 partials [NCH2][B][HW2]
#define F_AP2T  (F_AP2S + NCH2*B_*HW2)
#define F_CP1S  (F_AP2T + NCH2*B_*HW2)     // Cs1 partials [B][C1][NT1]
#define F_CP1T  (F_CP1S + B_*C1*NT1)
#define F_CP2S  (F_CP1T + B_*C1*NT1)       // Cs2 (complete) [B][C2]
#define F_CP2T  (F_CP2S + B_*C2)
#define F_GS1S  (F_CP2T + B_*C2)           // final Gs1 (unscaled As sums) [B][HW1]
#define F_GS1T  (F_GS1S + B_*HW1)
#define F_GS2S  (F_GS1T + B_*HW1)          // final Gs2 [B][HW2]
#define F_GS2T  (F_GS2S + B_*HW2)
#define F_MS1   (F_GS2T + B_*HW2)
#define F_MC1   (F_MS1 + B_*HW1)
#define F_MS2   (F_MC1 + B_*C1)
#define F_MC2   (F_MS2 + B_*HW2)
#define F_END   (F_MC2 + B_*C2)
#define FAST_WS_BYTES ((size_t)F_END * 4)

// ---------------- fallback ws layout (round-2, atomic-based) ----------------
#define ACC   0
#define AS1S  4
#define AS1T  (AS1S + B_*HW1)
#define CS1S  (AS1T + B_*HW1)
#define CS1T  (CS1S + B_*C1)
#define AS2S  (CS1T + B_*C1)
#define AS2T  (AS2S + B_*HW2)
#define CS2S  (AS2T + B_*HW2)
#define CS2T  (CS2S + B_*C2)
#define ZEND  (CS2T + B_*C2)
#define MS1   ZEND
#define MC1   (MS1 + B_*HW1)
#define MS2   (MC1 + B_*C1)
#define MC2   (MS2 + B_*HW2)

__device__ __forceinline__ float wave_reduce_sum(float v) {
#pragma unroll
    for (int off = 1; off < 64; off <<= 1) v += __shfl_xor(v, off, 64);
    return v;
}
__device__ __forceinline__ float wave_reduce_max(float v) {
#pragma unroll
    for (int off = 1; off < 64; off <<= 1) v = fmaxf(v, __shfl_xor(v, off, 64));
    return v;
}
__device__ __forceinline__ float block_reduce_sum(float v, float* red) {
    const int lane = threadIdx.x & 63, wid = threadIdx.x >> 6;
    v = wave_reduce_sum(v);
    if (lane == 0) red[wid] = v;
    __syncthreads();
    v = red[0] + red[1] + red[2] + red[3];
    __syncthreads();
    return v;
}
__device__ __forceinline__ float block_reduce_max(float v, float* red) {
    const int lane = threadIdx.x & 63, wid = threadIdx.x >> 6;
    v = wave_reduce_max(v);
    if (lane == 0) red[wid] = v;
    __syncthreads();
    v = fmaxf(fmaxf(red[0], red[1]), fmaxf(red[2], red[3]));
    __syncthreads();
    return v;
}

// ============================== FAST PATH ==============================

// stats: hot loop = 16 independent float4 loads + abs/add. No atomics.
// As partials: plain float4 stores. Cs partials: LDS transpose + shuffle.
template<int C, int HW, int NT>
__device__ void stats_fast_level(const float* __restrict__ s, const float* __restrict__ t,
                                 float* __restrict__ APs, float* __restrict__ APt,
                                 float* __restrict__ CPs, float* __restrict__ CPt,
                                 int b, int tile, int chunk, float (*part)[256]) {
    const int tid = threadIdx.x, lane = tid & 63, wid = tid >> 6;
    const int hw0 = tile * HWT + tid * 4;
    const int c0 = chunk * CCH;
    const size_t base = ((size_t)(b * C + c0)) * HW + hw0;
    const float4* ps = reinterpret_cast<const float4*>(s + base);
    const float4* pt = reinterpret_cast<const float4*>(t + base);
    const int cstride = HW / 4;

    float as0 = 0.f, as1 = 0.f, as2 = 0.f, as3 = 0.f;
    float at0 = 0.f, at1 = 0.f, at2 = 0.f, at3 = 0.f;
    float css[CCH], cst[CCH];

#pragma unroll
    for (int ci = 0; ci < CCH; ++ci) {
        float4 vs = ps[(size_t)ci * cstride];
        float4 vt = pt[(size_t)ci * cstride];
        float a0 = fabsf(vs.x), a1 = fabsf(vs.y), a2 = fabsf(vs.z), a3 = fabsf(vs.w);
        float b0 = fabsf(vt.x), b1 = fabsf(vt.y), b2 = fabsf(vt.z), b3 = fabsf(vt.w);
        as0 += a0; as1 += a1; as2 += a2; as3 += a3;
        at0 += b0; at1 += b1; at2 += b2; at3 += b3;
        css[ci] = (a0 + a1) + (a2 + a3);
        cst[ci] = (b0 + b1) + (b2 + b3);
    }

    const size_t ap = ((size_t)chunk * B_ + b) * HW + hw0;
    *reinterpret_cast<float4*>(APs + ap) = make_float4(as0, as1, as2, as3);
    *reinterpret_cast<float4*>(APt + ap) = make_float4(at0, at1, at2, at3);

#pragma unroll
    for (int ci = 0; ci < CCH; ++ci) {
        part[ci][tid] = css[ci];
        part[CCH + ci][tid] = cst[ci];
    }
    __syncthreads();
#pragma unroll
    for (int k = 0; k < 4; ++k) {            // 4 waves * 4 rows = 16 rows
        const int r = wid * 4 + k;
        const float* cb = part[r];
        float v = (cb[lane] + cb[lane + 64]) + (cb[lane + 128] + cb[lane + 192]);
        v = wave_reduce_sum(v);
        if (lane == 0) {
            const int cc = r & (CCH - 1);
            float* dst = (r < CCH) ? CPs : CPt;
            dst[((size_t)b * C + c0 + cc) * NT + tile] = v;
        }
    }
}

__global__ __launch_bounds__(256) void stats_fast(const float* __restrict__ s1, const float* __restrict__ t1,
                                                  const float* __restrict__ s2, const float* __restrict__ t2,
                                                  float* ws) {
    __shared__ float part[2 * CCH][256];   // 16 KB
    const int bid = blockIdx.x;
    if (bid < NB1) {   // level 1: 8 b * 4 tiles * 32 chunks
        const int b = bid >> 7, rem = bid & 127, tile = rem >> 5, chunk = rem & 31;
        stats_fast_level<C1, HW1, NT1>(s1, t1, ws + F_AP1S, ws + F_AP1T, ws + F_CP1S, ws + F_CP1T,
                                       b, tile, chunk, part);
    } else {           // level 2: 8 b * 64 chunks
        const int bid2 = bid - NB1;
        const int b = bid2 >> 6, chunk = bid2 & 63;
        stats_fast_level<C2, HW2, NT2>(s2, t2, ws + F_AP2S, ws + F_AP2T, ws + F_CP2S, ws + F_CP2T,
                                       b, 0, chunk, part);
    }
}

// reduce_as: fold As partials -> final Gs arrays. 80 blocks * 256 threads = 20480
// float4 outputs (level1: 16384, level2: 4096). Spreads the 12.6 MB partial read
// across the whole chip instead of 8 CUs.
__global__ __launch_bounds__(256) void reduce_as(float* __restrict__ ws) {
    const int gid = blockIdx.x * 256 + threadIdx.x;
    if (gid < 2 * B_ * (HW1 / 4)) {                    // level 1
        const int tt = gid >> 13, rem = gid & 8191;    // 8192 per tensor
        const int b = rem >> 10, q = rem & 1023;       // HW1/4 = 1024
        const float4* src = reinterpret_cast<const float4*>(ws + (tt ? F_AP1T : F_AP1S))
                            + (size_t)b * (HW1 / 4) + q;
        float4 acc = make_float4(0.f, 0.f, 0.f, 0.f);
#pragma unroll
        for (int k = 0; k < NCH1; ++k) {
            float4 v = src[(size_t)k * B_ * (HW1 / 4)];
            acc.x += v.x; acc.y += v.y; acc.z += v.z; acc.w += v.w;
        }
        reinterpret_cast<float4*>(ws + (tt ? F_GS1T : F_GS1S))[(size_t)b * (HW1 / 4) + q] = acc;
    } else {                                           // level 2
        const int g2 = gid - 2 * B_ * (HW1 / 4);
        const int tt = g2 >> 11, rem = g2 & 2047;      // 2048 per tensor
        const int b = rem >> 8, q = rem & 255;         // HW2/4 = 256
        const float4* src = reinterpret_cast<const float4*>(ws + (tt ? F_AP2T : F_AP2S))
                            + (size_t)b * (HW2 / 4) + q;
        float4 acc = make_float4(0.f, 0.f, 0.f, 0.f);
#pragma unroll
        for (int k = 0; k < NCH2; ++k) {
            float4 v = src[(size_t)k * B_ * (HW2 / 4)];
            acc.x += v.x; acc.y += v.y; acc.z += v.z; acc.w += v.w;
        }
        reinterpret_cast<float4*>(ws + (tt ? F_GS2T : F_GS2S))[(size_t)b * (HW2 / 4) + q] = acc;
    }
}

// softmax: read final Gs / Cs partials, compute lat partial + masks. 32 blocks.
__global__ __launch_bounds__(256) void softmax_fast(float* ws) {
    __shared__ float sa[HW1], sb[HW1];     // 32 KB
    __shared__ float red[4];
    const int bid = blockIdx.x;
    const int b = bid >> 2, m = bid & 3;
    const int tid = threadIdx.x;

    int n; float scale, mult; float* M;
    if (m == 0)      { n = HW1; scale = 1.0f / C1;  mult = (float)HW1; M = ws + F_MS1 + b * HW1; }
    else if (m == 1) { n = C1;  scale = 1.0f / HW1; mult = (float)C1;  M = ws + F_MC1 + b * C1;  }
    else if (m == 2) { n = HW2; scale = 1.0f / C2;  mult = (float)HW2; M = ws + F_MS2 + b * HW2; }
    else             { n = C2;  scale = 1.0f / HW2; mult = (float)C2;  M = ws + F_MC2 + b * C2;  }

    if (m == 0) {
        const float* As = ws + F_GS1S + b * HW1;
        const float* At = ws + F_GS1T + b * HW1;
        for (int i = tid; i < HW1; i += 256) { sa[i] = As[i] * scale; sb[i] = At[i] * scale; }
    } else if (m == 1) {
        if (tid < C1) {
            float4 v = *reinterpret_cast<const float4*>(ws + F_CP1S + ((size_t)b * C1 + tid) * 4);
            float4 w = *reinterpret_cast<const float4*>(ws + F_CP1T + ((size_t)b * C1 + tid) * 4);
            sa[tid] = ((v.x + v.y) + (v.z + v.w)) * scale;
            sb[tid] = ((w.x + w.y) + (w.z + w.w)) * scale;
        }
    } else if (m == 2) {
        const float* As = ws + F_GS2S + b * HW2;
        const float* At = ws + F_GS2T + b * HW2;
        for (int i = tid; i < HW2; i += 256) { sa[i] = As[i] * scale; sb[i] = At[i] * scale; }
    } else {
        for (int i = tid; i < C2; i += 256) {
            sa[i] = ws[F_CP2S + b * C2 + i] * scale;
            sb[i] = ws[F_CP2T + b * C2 + i] * scale;
        }
    }
    __syncthreads();

    const float invT = 2.0f;  // 1/T, T=0.5
    float latp = 0.f, mx = -3.0e38f;
    for (int i = tid; i < n; i += 256) {
        float d = sa[i] - sb[i];
        latp += d * d;
        mx = fmaxf(mx, (sa[i] + sb[i]) * invT);
    }
    const float mxall = block_reduce_max(mx, red);
    const float latall = block_reduce_sum(latp, red);
    if (tid == 0) ws[F_LATP + bid] = latall;

    float se = 0.f;
    for (int i = tid; i < n; i += 256) {
        se += expf((sa[i] + sb[i]) * invT - mxall);
    }
    const float seall = block_reduce_sum(se, red);
    const float inv = mult / seall;
    for (int i = tid; i < n; i += 256) {
        M[i] = expf((sa[i] + sb[i]) * invT - mxall) * inv;
    }
}

// slam: float4 hot loop, block reduce, per-block partial slot (no atomics)
template<int C, int HW>
__device__ void slam_fast_level(const float* __restrict__ s, const float* __restrict__ t,
                                const float* Ms, const float* Mc, float* slot,
                                int b, int tile, int chunk, float* mc, float* red) {
    const int tid = threadIdx.x;
    const int hw0 = tile * HWT + tid * 4;
    const int c0 = chunk * CCH;
    if (tid < CCH) mc[tid] = Mc[b * C + c0 + tid];
    __syncthreads();
    const size_t base = ((size_t)(b * C + c0)) * HW + hw0;
    const float4* ps = reinterpret_cast<const float4*>(s + base);
    const float4* pt = reinterpret_cast<const float4*>(t + base);
    const int cstride = HW / 4;

    float acc0 = 0.f, acc1 = 0.f, acc2 = 0.f, acc3 = 0.f;
#pragma unroll
    for (int ci = 0; ci < CCH; ++ci) {
        float4 vs = ps[(size_t)ci * cstride];
        float4 vt = pt[(size_t)ci * cstride];
        const float m = mc[ci];
        float d0 = vs.x - vt.x, d1 = vs.y - vt.y, d2 = vs.z - vt.z, d3 = vs.w - vt.w;
        acc0 = fmaf(m, d0 * d0, acc0);
        acc1 = fmaf(m, d1 * d1, acc1);
        acc2 = fmaf(m, d2 * d2, acc2);
        acc3 = fmaf(m, d3 * d3, acc3);
    }
    const float4 msv = *reinterpret_cast<const float4*>(Ms + b * HW + hw0);
    float acc = acc0 * msv.x + acc1 * msv.y + acc2 * msv.z + acc3 * msv.w;
    acc = block_reduce_sum(acc, red);
    if (tid == 0) *slot = acc;
}

__global__ __launch_bounds__(256) void slam_fast(const float* __restrict__ s1, const float* __restrict__ t1,
                                                 const float* __restrict__ s2, const float* __restrict__ t2,
                                                 float* ws) {
    __shared__ float mc[CCH];
    __shared__ float red[4];
    const int bid = blockIdx.x;
    if (bid < NB1) {
        const int b = bid >> 7, rem = bid & 127, tile = rem >> 5, chunk = rem & 31;
        slam_fast_level<C1, HW1>(s1, t1, ws + F_MS1, ws + F_MC1, ws + F_SL1P + bid, b, tile, chunk, mc, red);
    } else {
        const int bid2 = bid - NB1;
        const int b = bid2 >> 6, chunk = bid2 & 63;
        slam_fast_level<C2, HW2>(s2, t2, ws + F_MS2, ws + F_MC2, ws + F_SL2P + bid2, b, 0, chunk, mc, red);
    }
}

__global__ __launch_bounds__(256) void final_fast(const float* __restrict__ ws, float* __restrict__ out) {
    __shared__ float red[4];
    const int tid = threadIdx.x;
    float lat = 0.f, p1 = 0.f, p2 = 0.f;
    for (int i = tid; i < 32; i += 256)   lat += ws[F_LATP + i];
    for (int i = tid; i < NB1; i += 256)  p1 += ws[F_SL1P + i];
    for (int i = tid; i < NB2; i += 256)  p2 += ws[F_SL2P + i];
    lat = block_reduce_sum(lat, red);
    p1 = block_reduce_sum(p1, red);
    p2 = block_reduce_sum(p2, red);
    if (tid == 0) {
        const float lam = sqrtf(p1) + sqrtf(p2);
        const float att = (4e-4f * lat + 2e-2f * lam) / 8.0f / 2.0f;
        out[0] = att * 8.0f;
        out[1] = att;
    }
}

// ============================== FALLBACK (round-2, proven) ==============================

template<int C, int HW>
__device__ void stats_level_fb(const float* __restrict__ s, const float* __restrict__ t,
                               float* As_s, float* As_t, float* Cs_s, float* Cs_t,
                               int b, int tile, int chunk, float (*part)[8][256]) {
    const int tid = threadIdx.x, lane = tid & 63, wid = tid >> 6;
    const int hw0 = tile * HWT + tid * 4;
    const int c0 = chunk * 16;
    const size_t base = ((size_t)(b * C + c0)) * HW + hw0;
    const float4* ps = reinterpret_cast<const float4*>(s + base);
    const float4* pt = reinterpret_cast<const float4*>(t + base);
    const int cstride = HW / 4;

    float as_s[4] = {0.f, 0.f, 0.f, 0.f};
    float as_t[4] = {0.f, 0.f, 0.f, 0.f};

#pragma unroll
    for (int sub = 0; sub < 2; ++sub) {
#pragma unroll
        for (int ci = 0; ci < 8; ++ci) {
            const int cc = sub * 8 + ci;
            float4 vs = ps[(size_t)cc * cstride];
            float4 vt = pt[(size_t)cc * cstride];
            float a0 = fabsf(vs.x), a1 = fabsf(vs.y), a2 = fabsf(vs.z), a3 = fabsf(vs.w);
            float b0 = fabsf(vt.x), b1 = fabsf(vt.y), b2 = fabsf(vt.z), b3 = fabsf(vt.w);
            as_s[0] += a0; as_s[1] += a1; as_s[2] += a2; as_s[3] += a3;
            as_t[0] += b0; as_t[1] += b1; as_t[2] += b2; as_t[3] += b3;
            part[0][ci][tid] = (a0 + a1) + (a2 + a3);
            part[1][ci][tid] = (b0 + b1) + (b2 + b3);
        }
        __syncthreads();
#pragma unroll
        for (int k = 0; k < 4; ++k) {
            const int col = (wid << 2) | k;
            const int tt = col >> 3, cc = col & 7;
            const float* cb = &part[tt][cc][0];
            float v = (cb[lane] + cb[lane + 64]) + (cb[lane + 128] + cb[lane + 192]);
            v = wave_reduce_sum(v);
            if (lane == 0) {
                float* dst = tt ? Cs_t : Cs_s;
                atomicAdd(&dst[b * C + c0 + sub * 8 + cc], v);
            }
        }
        __syncthreads();
    }
    const int hwb = b * HW + hw0;
#pragma unroll
    for (int j = 0; j < 4; ++j) atomicAdd(&As_s[hwb + j], as_s[j]);
#pragma unroll
    for (int j = 0; j < 4; ++j) atomicAdd(&As_t[hwb + j], as_t[j]);
}

__global__ __launch_bounds__(256) void stats_fb(const float* __restrict__ s1, const float* __restrict__ t1,
                                                const float* __restrict__ s2, const float* __restrict__ t2,
                                                float* ws) {
    __shared__ float part[2][8][256];
    const int bid = blockIdx.x;
    if (bid < 512) {
        const int b = bid >> 6, rem = bid & 63, tile = rem >> 4, chunk = rem & 15;
        stats_level_fb<C1, HW1>(s1, t1, ws + AS1S, ws + AS1T, ws + CS1S, ws + CS1T, b, tile, chunk, part);
    } else {
        const int bid2 = bid - 512;
        const int b = bid2 >> 5, chunk = bid2 & 31;
        stats_level_fb<C2, HW2>(s2, t2, ws + AS2S, ws + AS2T, ws + CS2S, ws + CS2T, b, 0, chunk, part);
    }
}

__global__ __launch_bounds__(256) void softmax_fb(float* ws) {
    __shared__ float red[4];
    const int bid = blockIdx.x;
    const int b = bid >> 2, m = bid & 3;
    const float* xa; const float* xb; float* M;
    int n; float scale, mult;
    if (m == 0)      { xa = ws + AS1S + b * HW1; xb = ws + AS1T + b * HW1; M = ws + MS1 + b * HW1; n = HW1; scale = 1.0f / C1;  mult = (float)HW1; }
    else if (m == 1) { xa = ws + CS1S + b * C1;  xb = ws + CS1T + b * C1;  M = ws + MC1 + b * C1;  n = C1;  scale = 1.0f / HW1; mult = (float)C1;  }
    else if (m == 2) { xa = ws + AS2S + b * HW2; xb = ws + AS2T + b * HW2; M = ws + MS2 + b * HW2; n = HW2; scale = 1.0f / C2;  mult = (float)HW2; }
    else             { xa = ws + CS2S + b * C2;  xb = ws + CS2T + b * C2;  M = ws + MC2 + b * C2;  n = C2;  scale = 1.0f / HW2; mult = (float)C2;  }

    const int tid = threadIdx.x;
    const float invT = 2.0f;
    float latp = 0.f, mx = -3.0e38f;
    for (int i = tid; i < n; i += 256) {
        float a = xa[i] * scale, c = xb[i] * scale;
        float d = a - c; latp += d * d;
        mx = fmaxf(mx, (a + c) * invT);
    }
    const float mxall = block_reduce_max(mx, red);
    const float latall = block_reduce_sum(latp, red);
    if (tid == 0) atomicAdd(&ws[ACC + 0], latall);

    float se = 0.f;
    for (int i = tid; i < n; i += 256) {
        float x = (xa[i] + xb[i]) * scale * invT;
        se += expf(x - mxall);
    }
    const float seall = block_reduce_sum(se, red);
    const float inv = mult / seall;
    for (int i = tid; i < n; i += 256) {
        float x = (xa[i] + xb[i]) * scale * invT;
        M[i] = expf(x - mxall) * inv;
    }
}

template<int C, int HW>
__device__ void slam_level_fb(const float* __restrict__ s, const float* __restrict__ t,
                              const float* Ms, const float* Mc, float* slam_acc,
                              int b, int tile, int chunk, float* mc, float* red) {
    const int tid = threadIdx.x;
    const int hw0 = tile * HWT + tid * 4;
    const int c0 = chunk * 16;
    if (tid < 16) mc[tid] = Mc[b * C + c0 + tid];
    __syncthreads();
    const size_t base = ((size_t)(b * C + c0)) * HW + hw0;
    const float4* ps = reinterpret_cast<const float4*>(s + base);
    const float4* pt = reinterpret_cast<const float4*>(t + base);
    const int cstride = HW / 4;
    float acc0 = 0.f, acc1 = 0.f, acc2 = 0.f, acc3 = 0.f;
#pragma unroll
    for (int ci = 0; ci < 16; ++ci) {
        float4 vs = ps[(size_t)ci * cstride];
        float4 vt = pt[(size_t)ci * cstride];
        const float m = mc[ci];
        float d0 = vs.x - vt.x, d1 = vs.y - vt.y, d2 = vs.z - vt.z, d3 = vs.w - vt.w;
        acc0 = fmaf(m, d0 * d0, acc0);
        acc1 = fmaf(m, d1 * d1, acc1);
        acc2 = fmaf(m, d2 * d2, acc2);
        acc3 = fmaf(m, d3 * d3, acc3);
    }
    const float4 msv = *reinterpret_cast<const float4*>(Ms + b * HW + hw0);
    float acc = acc0 * msv.x + acc1 * msv.y + acc2 * msv.z + acc3 * msv.w;
    acc = block_reduce_sum(acc, red);
    if (tid == 0) atomicAdd(slam_acc, acc);
}

__global__ __launch_bounds__(256) void slam_fb(const float* __restrict__ s1, const float* __restrict__ t1,
                                               const float* __restrict__ s2, const float* __restrict__ t2,
                                               float* ws) {
    __shared__ float mc[16];
    __shared__ float red[4];
    const int bid = blockIdx.x;
    if (bid < 512) {
        const int b = bid >> 6, rem = bid & 63, tile = rem >> 4, chunk = rem & 15;
        slam_level_fb<C1, HW1>(s1, t1, ws + MS1, ws + MC1, ws + ACC + 1, b, tile, chunk, mc, red);
    } else {
        const int bid2 = bid - 512;
        const int b = bid2 >> 5, chunk = bid2 & 31;
        slam_level_fb<C2, HW2>(s2, t2, ws + MS2, ws + MC2, ws + ACC + 2, b, 0, chunk, mc, red);
    }
}

__global__ void final_fb(const float* __restrict__ ws, float* __restrict__ out) {
    if (threadIdx.x == 0 && blockIdx.x == 0) {
        const float lat = ws[ACC + 0];
        const float lam = sqrtf(ws[ACC + 1]) + sqrtf(ws[ACC + 2]);
        const float att = (4e-4f * lat + 2e-2f * lam) / 8.0f / 2.0f;
        out[0] = att * 8.0f;
        out[1] = att;
    }
}

// ============================== launch ==============================

extern "C" void kernel_launch(void* const* d_in, const int* in_sizes, int n_in,
                              void* d_out, int out_size, void* d_ws, size_t ws_size,
                              hipStream_t stream) {
    (void)in_sizes; (void)n_in; (void)out_size;
    const float* s1 = (const float*)d_in[1];
    const float* t1 = (const float*)d_in[2];
    const float* s2 = (const float*)d_in[3];
    const float* t2 = (const float*)d_in[4];
    float* ws = (float*)d_ws;
    float* out = (float*)d_out;

    if (ws_size >= FAST_WS_BYTES) {
        stats_fast<<<NBS, 256, 0, stream>>>(s1, t1, s2, t2, ws);
        reduce_as<<<80, 256, 0, stream>>>(ws);
        softmax_fast<<<32, 256, 0, stream>>>(ws);
        slam_fast<<<NBS, 256, 0, stream>>>(s1, t1, s2, t2, ws);
        final_fast<<<1, 256, 0, stream>>>(ws, out);
    } else {
        hipMemsetAsync(ws, 0, (size_t)ZEND * sizeof(float), stream);
        stats_fb<<<768, 256, 0, stream>>>(s1, t1, s2, t2, ws);
        softmax_fb<<<32, 256, 0, stream>>>(ws);
        slam_fb<<<768, 256, 0, stream>>>(s1, t1, s2, t2, ws);
        final_fb<<<1, 64, 0, stream>>>(ws, out);
    }
}